// Round 1
// baseline (822.251 us; speedup 1.0000x reference)
//
#include <hip/hip_runtime.h>
#include <hip/hip_bf16.h>

// Problem constants (GATLayer): B=8, C=2048, IN=OUT=128, H=4, D=32
constexpr int B_  = 8;
constexpr int C_  = 2048;
constexpr int IND = 128;   // IN_DIM == H*D == OUT_DIM
constexpr int H_  = 4;
constexpr int D_  = 32;
constexpr int M_  = B_ * C_;           // 16384 rows
constexpr float QSCALE = 0.17677669529663687f;  // 1/sqrt(32)
constexpr float L2E = 1.4426950408889634f;

// attention tiling
constexpr int TQ = 64;      // q rows per block
constexpr int TK = 32;      // k rows per LDS tile
constexpr int KSPLIT = 4;   // split-K factor
constexpr int KPB = C_ / KSPLIT;  // 512 k per block

// ---------------------------------------------------------------------------
// K1: fused QKV projection.  x(16384,128) @ {Wq,Wk,Wv}(128,128) -> Q,K,V
// Q is pre-scaled by 1/sqrt(D). Layout (B,C,128) with col = h*32+d.
// Block: 256 threads handles 32 rows; each thread a 4x4 register tile.
__global__ __launch_bounds__(256) void qkv_proj_kernel(
    const float* __restrict__ x,
    const float* __restrict__ Wq, const float* __restrict__ Wk,
    const float* __restrict__ Wv,
    float* __restrict__ Q, float* __restrict__ K, float* __restrict__ V)
{
    __shared__ float xs[32][IND];   // 16 KB
    const int t = threadIdx.x;
    const size_t row0 = (size_t)blockIdx.x * 32;

    const float4* xsrc = (const float4*)(x + row0 * IND);
    float4* xd = (float4*)&xs[0][0];
#pragma unroll
    for (int i = 0; i < 4; ++i) xd[t + i * 256] = xsrc[t + i * 256];
    __syncthreads();

    const int rg = t >> 5;          // 0..7
    const int cg = t & 31;          // 0..31
    const int r0 = rg * 4, c0 = cg * 4;

    const float* Ws[3] = {Wq, Wk, Wv};
    float* Os[3] = {Q, K, V};

#pragma unroll
    for (int w = 0; w < 3; ++w) {
        const float* __restrict__ W = Ws[w];
        float acc[4][4] = {};
#pragma unroll 4
        for (int k = 0; k < IND; ++k) {
            const float4 wv = *(const float4*)(W + k * IND + c0);
#pragma unroll
            for (int i = 0; i < 4; ++i) {
                const float xr = xs[r0 + i][k];
                acc[i][0] += xr * wv.x;
                acc[i][1] += xr * wv.y;
                acc[i][2] += xr * wv.z;
                acc[i][3] += xr * wv.w;
            }
        }
        const float scale = (w == 0) ? QSCALE : 1.0f;
        float* O = Os[w] + row0 * IND;
#pragma unroll
        for (int i = 0; i < 4; ++i) {
            float4 o;
            o.x = acc[i][0] * scale; o.y = acc[i][1] * scale;
            o.z = acc[i][2] * scale; o.w = acc[i][3] * scale;
            *(float4*)(O + (size_t)(r0 + i) * IND + c0) = o;
        }
    }
}

// ---------------------------------------------------------------------------
// K2: adjacency-gated flash attention (fixed-base softmax: scores are small,
// |s| <~ 2, so exp(s) cannot overflow -> no online max needed).
// Block: 256 threads = 4 heads x 64 q-rows. Wave = one head, so K/V LDS
// reads are wave-uniform broadcasts. Split-K over blockIdx.z.
__global__ __launch_bounds__(256, 3) void attn_kernel(
    const float* __restrict__ Q, const float* __restrict__ K,
    const float* __restrict__ V, const float* __restrict__ adj,
    float* __restrict__ Opart, float* __restrict__ lpart)
{
    __shared__ float Ks[TK][IND];        // 16 KB
    __shared__ float Vs[TK][IND];        // 16 KB
    __shared__ float adjs[TK][TQ + 1];   // 8.3 KB, transposed + padded

    const int t  = threadIdx.x;
    const int h  = t >> 6;               // 0..3 (one head per wave)
    const int ql = t & 63;               // 0..63
    const int qt = blockIdx.x;           // 0..31
    const int b  = blockIdx.y;           // 0..7
    const int kz = blockIdx.z;           // 0..3
    const int q0 = qt * TQ;
    const int k0base = kz * KPB;

    // Q row for this (h, q) into registers (pre-scaled in K1)
    float4 qr[8];
    const float4* qsrc =
        (const float4*)(Q + ((size_t)(b * C_) + q0 + ql) * IND + h * D_);
#pragma unroll
    for (int i = 0; i < 8; ++i) qr[i] = qsrc[i];

    float4 o[8] = {};
    float l = 0.f;

    const int ks = t & 31;   // staging coords for adj
    const int qs = t >> 5;

    for (int kt = 0; kt < KPB / TK; ++kt) {
        const int k0 = k0base + kt * TK;
        __syncthreads();
        {
            const float4* Ksrc = (const float4*)(K + ((size_t)(b * C_) + k0) * IND);
            const float4* Vsrc = (const float4*)(V + ((size_t)(b * C_) + k0) * IND);
            float4* Kd = (float4*)&Ks[0][0];
            float4* Vd = (float4*)&Vs[0][0];
#pragma unroll
            for (int i = 0; i < 4; ++i) {
                Kd[t + i * 256] = Ksrc[t + i * 256];
                Vd[t + i * 256] = Vsrc[t + i * 256];
            }
            // adj tile: global-coalesced over k, LDS write stride 65 -> no conflicts
#pragma unroll
            for (int i = 0; i < 8; ++i) {
                const int qq = qs + i * 8;
                adjs[ks][qq] = adj[((size_t)b * C_ + q0 + qq) * C_ + k0 + ks];
            }
        }
        __syncthreads();

#pragma unroll 2
        for (int kk = 0; kk < TK; ++kk) {
            const float4* Kr = (const float4*)&Ks[kk][h * D_];
            float s = 0.f;
#pragma unroll
            for (int d4 = 0; d4 < 8; ++d4) {
                const float4 kv = Kr[d4];
                s += qr[d4].x * kv.x + qr[d4].y * kv.y +
                     qr[d4].z * kv.z + qr[d4].w * kv.w;
            }
            s *= adjs[kk][ql];
            s = (s > 0.f) ? s : 0.2f * s;           // LeakyReLU(0.2)
            const float p = exp2f(s * L2E);          // e^s, no max subtraction
            l += p;
            const float4* Vr = (const float4*)&Vs[kk][h * D_];
#pragma unroll
            for (int d4 = 0; d4 < 8; ++d4) {
                const float4 vv = Vr[d4];
                o[d4].x += p * vv.x; o[d4].y += p * vv.y;
                o[d4].z += p * vv.z; o[d4].w += p * vv.w;
            }
        }
    }

    // partial out: Opart[kz][(b*H+h)*C + q][32], lpart[kz][(b*H+h)*C + q]
    const size_t base = (size_t)kz * (B_ * H_ * C_) +
                        ((size_t)(b * H_ + h) * C_ + q0 + ql);
    float4* Od = (float4*)(Opart + base * D_);
#pragma unroll
    for (int i = 0; i < 8; ++i) Od[i] = o[i];
    lpart[base] = l;
}

// ---------------------------------------------------------------------------
// K3: combine split-K partials:  AO = (sum_kz O_kz) / (sum_kz l_kz)
__global__ __launch_bounds__(256) void combine_kernel(
    const float* __restrict__ Opart, const float* __restrict__ lpart,
    float* __restrict__ AO)
{
    const int idx = blockIdx.x * 256 + threadIdx.x;   // (b*H+h)*C + q
    const int q  = idx & (C_ - 1);
    const int bh = idx >> 11;
    const int h  = bh & (H_ - 1);
    const int b  = bh >> 2;

    float4 acc[8] = {};
    float lsum = 0.f;
#pragma unroll
    for (int kz = 0; kz < KSPLIT; ++kz) {
        const size_t base = (size_t)kz * (B_ * H_ * C_) + idx;
        lsum += lpart[base];
        const float4* Od = (const float4*)(Opart + base * D_);
#pragma unroll
        for (int i = 0; i < 8; ++i) {
            const float4 v = Od[i];
            acc[i].x += v.x; acc[i].y += v.y; acc[i].z += v.z; acc[i].w += v.w;
        }
    }
    const float inv = 1.f / lsum;
    float4* dst = (float4*)(AO + ((size_t)(b * C_) + q) * IND + h * D_);
#pragma unroll
    for (int i = 0; i < 8; ++i) {
        float4 v;
        v.x = acc[i].x * inv; v.y = acc[i].y * inv;
        v.z = acc[i].z * inv; v.w = acc[i].w * inv;
        dst[i] = v;
    }
}

// ---------------------------------------------------------------------------
// K4: output projection + bias.  out = AO(16384,128) @ Wo(128,128) + bo
__global__ __launch_bounds__(256) void out_proj_kernel(
    const float* __restrict__ AO, const float* __restrict__ Wo,
    const float* __restrict__ bo, float* __restrict__ out)
{
    __shared__ float xs[32][IND];
    const int t = threadIdx.x;
    const size_t row0 = (size_t)blockIdx.x * 32;

    const float4* xsrc = (const float4*)(AO + row0 * IND);
    float4* xd = (float4*)&xs[0][0];
#pragma unroll
    for (int i = 0; i < 4; ++i) xd[t + i * 256] = xsrc[t + i * 256];
    __syncthreads();

    const int rg = t >> 5, cg = t & 31;
    const int r0 = rg * 4, c0 = cg * 4;

    float acc[4][4] = {};
#pragma unroll 4
    for (int k = 0; k < IND; ++k) {
        const float4 wv = *(const float4*)(Wo + k * IND + c0);
#pragma unroll
        for (int i = 0; i < 4; ++i) {
            const float xr = xs[r0 + i][k];
            acc[i][0] += xr * wv.x;
            acc[i][1] += xr * wv.y;
            acc[i][2] += xr * wv.z;
            acc[i][3] += xr * wv.w;
        }
    }
    const float4 bv = *(const float4*)(bo + c0);
    float* O = out + row0 * IND;
#pragma unroll
    for (int i = 0; i < 4; ++i) {
        float4 o;
        o.x = acc[i][0] + bv.x; o.y = acc[i][1] + bv.y;
        o.z = acc[i][2] + bv.z; o.w = acc[i][3] + bv.w;
        *(float4*)(O + (size_t)(r0 + i) * IND + c0) = o;
    }
}

// ---------------------------------------------------------------------------
extern "C" void kernel_launch(void* const* d_in, const int* in_sizes, int n_in,
                              void* d_out, int out_size, void* d_ws, size_t ws_size,
                              hipStream_t stream) {
    const float* x   = (const float*)d_in[0];
    const float* adj = (const float*)d_in[1];
    const float* Wq  = (const float*)d_in[2];
    const float* Wk  = (const float*)d_in[3];
    const float* Wv  = (const float*)d_in[4];
    const float* Wo  = (const float*)d_in[5];
    const float* bo  = (const float*)d_in[6];
    float* out = (float*)d_out;

    // workspace layout (floats): Q,K,V,AO: 2,097,152 each; Opart 8,388,608; lpart 262,144
    float* ws = (float*)d_ws;
    float* Q     = ws;
    float* K     = Q  + (size_t)M_ * IND;
    float* V     = K  + (size_t)M_ * IND;
    float* AO    = V  + (size_t)M_ * IND;
    float* Opart = AO + (size_t)M_ * IND;
    float* lpart = Opart + (size_t)KSPLIT * B_ * H_ * C_ * D_;

    hipLaunchKernelGGL(qkv_proj_kernel, dim3(M_ / 32), dim3(256), 0, stream,
                       x, Wq, Wk, Wv, Q, K, V);
    hipLaunchKernelGGL(attn_kernel, dim3(C_ / TQ, B_, KSPLIT), dim3(256), 0, stream,
                       Q, K, V, adj, Opart, lpart);
    hipLaunchKernelGGL(combine_kernel, dim3(B_ * H_ * C_ / 256), dim3(256), 0, stream,
                       Opart, lpart, AO);
    hipLaunchKernelGGL(out_proj_kernel, dim3(M_ / 32), dim3(256), 0, stream,
                       AO, Wo, bo, out);
}

// Round 3
// 452.452 us; speedup vs baseline: 1.8173x; 1.8173x over previous
//
#include <hip/hip_runtime.h>
#include <hip/hip_bf16.h>

// Problem constants (GATLayer): B=8, C=2048, IN=OUT=128, H=4, D=32
constexpr int B_  = 8;
constexpr int C_  = 2048;
constexpr int IND = 128;
constexpr int H_  = 4;
constexpr int D_  = 32;
constexpr int M_  = B_ * C_;          // 16384 tokens
constexpr float QSCALE = 0.17677669529663687f;   // 1/sqrt(32)
constexpr float L2E    = 1.4426950408889634f;
constexpr float QL2    = QSCALE * L2E;           // folded: exp2 needs no mul

constexpr int KSPLIT = 4;
constexpr int KPB = C_ / KSPLIT;      // 512 keys per block

typedef __attribute__((ext_vector_type(8))) short short8;
typedef __attribute__((ext_vector_type(4))) short s4t;
typedef __attribute__((ext_vector_type(4))) float f4t;
typedef __attribute__((ext_vector_type(4))) unsigned short us4;

// Device pass has this builtin (verified: round-2 device compile succeeded);
// host pass doesn't advertise it via __has_builtin, so give host a dummy.
#if __has_builtin(__builtin_amdgcn_mfma_f32_16x16x16bf16_1k)
#define MFMA16(a, b, c) __builtin_amdgcn_mfma_f32_16x16x16bf16_1k(a, b, c, 0, 0, 0)
#else
#define MFMA16(a, b, c) (c)   // host-pass placeholder, never executed
#endif

__device__ __forceinline__ unsigned short f2bf(float f) {
    union { float f; unsigned u; } v; v.f = f;
    unsigned u = v.u + 0x7fffu + ((v.u >> 16) & 1u);   // RNE
    return (unsigned short)(u >> 16);
}

// ---------------------------------------------------------------------------
// K1: fused QKV projection (fp32 compute, bf16 outputs).
// Qb scaled by (1/sqrt(D))*log2(e).  Vt is V transposed: Vt[b][d(128)][c].
__global__ __launch_bounds__(256) void qkv_proj_kernel(
    const float* __restrict__ x,
    const float* __restrict__ Wq, const float* __restrict__ Wk,
    const float* __restrict__ Wv,
    unsigned short* __restrict__ Qb, unsigned short* __restrict__ Kb,
    unsigned short* __restrict__ Vt)
{
    __shared__ float xs[32][IND];   // 16 KB
    const int t = threadIdx.x;
    const size_t row0 = (size_t)blockIdx.x * 32;

    const float4* xsrc = (const float4*)(x + row0 * IND);
    float4* xd = (float4*)&xs[0][0];
#pragma unroll
    for (int i = 0; i < 4; ++i) xd[t + i * 256] = xsrc[t + i * 256];
    __syncthreads();

    const int rg = t >> 5, cg = t & 31;
    const int r0 = rg * 4, c0 = cg * 4;
    const int b  = (int)(row0 >> 11);     // row0 / 2048
    const int cb = (int)(row0 & 2047);

#pragma unroll
    for (int w = 0; w < 3; ++w) {
        const float* __restrict__ W = (w == 0) ? Wq : (w == 1) ? Wk : Wv;
        float acc[4][4] = {};
#pragma unroll 4
        for (int k = 0; k < IND; ++k) {
            const float4 wv = *(const float4*)(W + k * IND + c0);
#pragma unroll
            for (int i = 0; i < 4; ++i) {
                const float xr = xs[r0 + i][k];
                acc[i][0] += xr * wv.x;
                acc[i][1] += xr * wv.y;
                acc[i][2] += xr * wv.z;
                acc[i][3] += xr * wv.w;
            }
        }
        if (w == 2) {
            // transposed store: Vt[(b*128 + d)*C + c], 4 consecutive tokens
#pragma unroll
            for (int jj = 0; jj < 4; ++jj) {
                us4 v;
#pragma unroll
                for (int i = 0; i < 4; ++i) v[i] = f2bf(acc[i][jj]);
                *(us4*)(Vt + ((size_t)(b * IND + c0 + jj)) * C_ + cb + r0) = v;
            }
        } else {
            const float sc = (w == 0) ? QL2 : 1.0f;
            unsigned short* O = (w == 0) ? Qb : Kb;
#pragma unroll
            for (int i = 0; i < 4; ++i) {
                us4 v;
#pragma unroll
                for (int j = 0; j < 4; ++j) v[j] = f2bf(acc[i][j] * sc);
                *(us4*)(O + (row0 + r0 + i) * IND + c0) = v;
            }
        }
    }
}

// ---------------------------------------------------------------------------
// K2: MFMA flash attention, scores computed TRANSPOSED so the probability
// tile lands directly in the 16x16x16 PV A-fragment layout. No LDS.
// Block = 256 threads = 4 waves; wave s owns q-subtile of 16 rows, all heads.
__global__ __launch_bounds__(256) void attn_kernel(
    const unsigned short* __restrict__ Qb, const unsigned short* __restrict__ Kb,
    const unsigned short* __restrict__ Vt, const float* __restrict__ adj,
    float* __restrict__ Opart, float* __restrict__ lpart)
{
    const int t  = threadIdx.x;
    const int s  = t >> 6;               // wave id = q-subtile
    const int l  = t & 63;
    const int lo = l & 15, hi = l >> 4;
    const int b  = blockIdx.y;
    const int kz = blockIdx.z;
    const int q0 = blockIdx.x * 64;
    const int qs = q0 + s * 16 + lo;     // this lane's q row (0..2047)
    const int k0base = kz * KPB;

    // Q fragments (B-operand of St MFMA): lane holds Q[qs][h*32 + hi*8 .. +8]
    short8 qf[4];
#pragma unroll
    for (int h = 0; h < 4; ++h)
        qf[h] = *(const short8*)(Qb + ((size_t)(b * C_) + qs) * IND + h * 32 + hi * 8);

    f4t acc[4][2];
#pragma unroll
    for (int h = 0; h < 4; ++h) { acc[h][0] = 0.f; acc[h][1] = 0.f; }
    float ls[4] = {0.f, 0.f, 0.f, 0.f};

    const float* adjrow = adj + ((size_t)(b * C_) + qs) * C_;
    const unsigned short* Krow = Kb + ((size_t)(b * C_) + lo) * IND + hi * 8;
    const unsigned short* Vrow = Vt + ((size_t)(b * IND) + lo) * C_;

    const int NIT = KPB / 16;
    f4t adjv = *(const f4t*)(adjrow + k0base + hi * 4);

    for (int it = 0; it < NIT; ++it) {
        const int k0  = k0base + it * 16;
        const int itn = (it + 1 < NIT) ? it + 1 : it;
        const f4t adjn = *(const f4t*)(adjrow + k0base + itn * 16 + hi * 4);

        short8 kf[4];
        s4t vf[4][2];
#pragma unroll
        for (int h = 0; h < 4; ++h) {
            kf[h]    = *(const short8*)(Krow + (size_t)k0 * IND + h * 32);
            vf[h][0] = *(const s4t*)(Vrow + (size_t)(h * 32) * C_ + k0 + hi * 4);
            vf[h][1] = *(const s4t*)(Vrow + (size_t)(h * 32 + 16) * C_ + k0 + hi * 4);
        }

#pragma unroll
        for (int h = 0; h < 4; ++h) {
            // St[k][q]: lane owns q=lo, k = k0 + hi*4 + r  (C-layout)
            f4t st = __builtin_amdgcn_mfma_f32_16x16x32_bf16(
                kf[h], qf[h], (f4t)0.f, 0, 0, 0);
            s4t pp;
#pragma unroll
            for (int r = 0; r < 4; ++r) {
                const float a = st[r] * adjv[r];         // adj gate (pre-leaky)
                const float m = fmaxf(a, 0.2f * a);      // LeakyReLU(0.2)
                const float p = exp2f(m);                // e^s (L2E pre-folded)
                ls[h] += p;
                pp[r] = (short)f2bf(p);
            }
            // PV: A=P (already in A-frag layout), B=V columns from Vt
            acc[h][0] = MFMA16(pp, vf[h][0], acc[h][0]);
            acc[h][1] = MFMA16(pp, vf[h][1], acc[h][1]);
        }
        adjv = adjn;
    }

    // reduce l over the 4 lane-groups (k quarters)
#pragma unroll
    for (int h = 0; h < 4; ++h) {
        ls[h] += __shfl_xor(ls[h], 16, 64);
        ls[h] += __shfl_xor(ls[h], 32, 64);
    }

    const size_t BHC   = (size_t)B_ * H_ * C_;
    const size_t obase = (size_t)kz * BHC;

    // each lane writes l for head=hi, q=qs
    const float lw = (hi == 0) ? ls[0] : (hi == 1) ? ls[1] : (hi == 2) ? ls[2] : ls[3];
    lpart[obase + (size_t)(b * H_ + hi) * C_ + qs] = lw;

    // O: PV C-layout: lane owns q = q0+s*16+hi*4+reg, d = h*32+dh*16+lo
#pragma unroll
    for (int h = 0; h < 4; ++h) {
        const size_t rb = obase + (size_t)(b * H_ + h) * C_ + q0 + s * 16 + hi * 4;
#pragma unroll
        for (int dh = 0; dh < 2; ++dh)
#pragma unroll
            for (int r = 0; r < 4; ++r)
                Opart[(rb + r) * D_ + dh * 16 + lo] = acc[h][dh][r];
    }
}

// ---------------------------------------------------------------------------
// K3: combine split-K partials:  AO = (sum_kz O_kz) / (sum_kz l_kz)
__global__ __launch_bounds__(256) void combine_kernel(
    const float* __restrict__ Opart, const float* __restrict__ lpart,
    float* __restrict__ AO)
{
    const int idx = blockIdx.x * 256 + threadIdx.x;   // (b*H+h)*C + q
    const int q  = idx & (C_ - 1);
    const int bh = idx >> 11;
    const int h  = bh & (H_ - 1);
    const int b  = bh >> 2;

    float4 acc[8] = {};
    float lsum = 0.f;
#pragma unroll
    for (int kz = 0; kz < KSPLIT; ++kz) {
        const size_t base = (size_t)kz * (B_ * H_ * C_) + idx;
        lsum += lpart[base];
        const float4* Od = (const float4*)(Opart + base * D_);
#pragma unroll
        for (int i = 0; i < 8; ++i) {
            const float4 v = Od[i];
            acc[i].x += v.x; acc[i].y += v.y; acc[i].z += v.z; acc[i].w += v.w;
        }
    }
    const float inv = 1.f / lsum;
    float4* dst = (float4*)(AO + ((size_t)(b * C_) + q) * IND + h * D_);
#pragma unroll
    for (int i = 0; i < 8; ++i) {
        float4 v;
        v.x = acc[i].x * inv; v.y = acc[i].y * inv;
        v.z = acc[i].z * inv; v.w = acc[i].w * inv;
        dst[i] = v;
    }
}

// ---------------------------------------------------------------------------
// K4: output projection + bias (fp32).  out = AO @ Wo + bo
__global__ __launch_bounds__(256) void out_proj_kernel(
    const float* __restrict__ AO, const float* __restrict__ Wo,
    const float* __restrict__ bo, float* __restrict__ out)
{
    __shared__ float xs[32][IND];
    const int t = threadIdx.x;
    const size_t row0 = (size_t)blockIdx.x * 32;

    const float4* xsrc = (const float4*)(AO + row0 * IND);
    float4* xd = (float4*)&xs[0][0];
#pragma unroll
    for (int i = 0; i < 4; ++i) xd[t + i * 256] = xsrc[t + i * 256];
    __syncthreads();

    const int rg = t >> 5, cg = t & 31;
    const int r0 = rg * 4, c0 = cg * 4;

    float acc[4][4] = {};
#pragma unroll 4
    for (int k = 0; k < IND; ++k) {
        const float4 wv = *(const float4*)(Wo + k * IND + c0);
#pragma unroll
        for (int i = 0; i < 4; ++i) {
            const float xr = xs[r0 + i][k];
            acc[i][0] += xr * wv.x;
            acc[i][1] += xr * wv.y;
            acc[i][2] += xr * wv.z;
            acc[i][3] += xr * wv.w;
        }
    }
    const float4 bv = *(const float4*)(bo + c0);
    float* O = out + row0 * IND;
#pragma unroll
    for (int i = 0; i < 4; ++i) {
        float4 o;
        o.x = acc[i][0] + bv.x; o.y = acc[i][1] + bv.y;
        o.z = acc[i][2] + bv.z; o.w = acc[i][3] + bv.w;
        *(float4*)(O + (size_t)(r0 + i) * IND + c0) = o;
    }
}

// ---------------------------------------------------------------------------
extern "C" void kernel_launch(void* const* d_in, const int* in_sizes, int n_in,
                              void* d_out, int out_size, void* d_ws, size_t ws_size,
                              hipStream_t stream) {
    const float* x   = (const float*)d_in[0];
    const float* adj = (const float*)d_in[1];
    const float* Wq  = (const float*)d_in[2];
    const float* Wk  = (const float*)d_in[3];
    const float* Wv  = (const float*)d_in[4];
    const float* Wo  = (const float*)d_in[5];
    const float* bo  = (const float*)d_in[6];
    float* out = (float*)d_out;

    // workspace: Qb,Kb,Vt bf16 (4MB each); AO fp32 8.4MB; Opart fp32 33.5MB; lpart 1MB
    unsigned short* Qb = (unsigned short*)d_ws;
    unsigned short* Kb = Qb + (size_t)M_ * IND;
    unsigned short* Vt = Kb + (size_t)M_ * IND;
    float* AO    = (float*)(Vt + (size_t)M_ * IND);
    float* Opart = AO + (size_t)M_ * IND;
    float* lpart = Opart + (size_t)KSPLIT * B_ * H_ * C_ * D_;

    hipLaunchKernelGGL(qkv_proj_kernel, dim3(M_ / 32), dim3(256), 0, stream,
                       x, Wq, Wk, Wv, Qb, Kb, Vt);
    hipLaunchKernelGGL(attn_kernel, dim3(C_ / 64, B_, KSPLIT), dim3(256), 0, stream,
                       Qb, Kb, Vt, adj, Opart, lpart);
    hipLaunchKernelGGL(combine_kernel, dim3(B_ * H_ * C_ / 256), dim3(256), 0, stream,
                       Opart, lpart, AO);
    hipLaunchKernelGGL(out_proj_kernel, dim3(M_ / 32), dim3(256), 0, stream,
                       AO, Wo, bo, out);
}